// Round 1
// 275.196 us; speedup vs baseline: 1.0376x; 1.0376x over previous
//
#include <hip/hip_runtime.h>
#include <math.h>

// EngramGating: B=16, S=16384, H=4, D=K=32. ntok = B*S = 262144.
// R6: VALU-bound per rocprof (VALUBusy 82%, HBM 22%). Replace the per-(t,h)
// DPP reduction trees (30 insts each + hazard bubbles + 32-way-redundant gate
// math) with an LDS transpose: matvec stays in k-parallel layout, then kk is
// written to a per-wave swizzled LDS tile and re-read with lane=(t,h,khalf) so
// Skk/Sqq/Skq accumulate in-lane (3 FMA/k). Gate math + transcendentals run
// once per (t,h) (trans insts/iter: 80 -> 5). All producer->consumer is
// same-wave (DS in-order) with lgkmcnt(0) fences; no barriers in the loop.

#define GRID    2048
#define EPS32   3.814697265625e-06f   // 32 * FLT_EPSILON
#define SQRT32  5.656854249492380f
#define LOG2E   1.4426950408889634f

__global__ __launch_bounds__(256) void engram_kernel(
    const float* __restrict__ emb,   // [ntok,32]
    const float* __restrict__ hid,   // [ntok,4,32]
    const float* __restrict__ Wv,    // [32,32]
    const float* __restrict__ bv,    // [32]
    const float* __restrict__ Wk,    // [4,32,32]
    const float* __restrict__ bk,    // [4,32]
    const float* __restrict__ g1,    // [4,32]
    const float* __restrict__ g2,    // [4,32]
    float* __restrict__ out,         // [ntok,4,32]
    int ntok)
{
    // Wl: 16 d-pairs x 160 channels x 2 (d parity) -- unchanged matvec layout
    __shared__ __align__(16) float Wl[16 * 160 * 2];   // 20480 B
    // KL: per-wave scratch. First 256 words: staged emb rows (8 x 32).
    // Later overwritten by kk tile: 32 rows (= t2*4+hh) x 32 k, 16B-block
    // XOR-swizzled (block c stored at c ^ (row&7)) for conflict-free b128.
    __shared__ __align__(16) float KL[4][32 * 32];     // 16384 B
    __shared__ __align__(16) float GL[4][32];          // gates, 512 B
    __shared__ __align__(16) float g12L[4 * 36];       // g1*g2, padded rows, 576 B

    const int tid  = threadIdx.x;
    const int wave = tid >> 6;
    const int lane = tid & 63;
    const int k    = lane & 31;
    const int h2   = lane >> 5;        // which half-wave (phase 1)
    const int mytok = h2 * 4;          // local token base (phase 1)

    // ---- stage weights (transpose), unchanged ----
    for (int i = tid; i < 5120; i += 256) {
        int d = i & 31;
        int r = i >> 5;                // r<128 -> Wk ch, else Wv ch
        float v = (r < 128) ? Wk[r * 32 + d] : Wv[(r - 128) * 32 + d];
        Wl[(((d >> 1) * 160 + r) << 1) | (d & 1)] = v;
    }
    if (tid < 128)
        g12L[(tid >> 5) * 36 + (tid & 31)] = g1[tid] * g2[tid];

    float bk_r[4];
    #pragma unroll
    for (int h = 0; h < 4; ++h) bk_r[h] = bk[h * 32 + k];
    const float bv_r = bv[k];
    __syncthreads();

    float* const KLw = KL[wave];
    // phase-2 role: lane = (row r2 = t2*4+hh, k-half kh)
    const int r2  = lane & 31;
    const int kh  = lane >> 5;
    const int t2  = r2 >> 2;           // token 0..7 within wave
    const int hh  = r2 & 3;            // head
    const int sw2 = r2 & 7;            // swizzle key (read side)

    const int tokens_per_block = ntok / GRID;        // 128
    const int iters = tokens_per_block >> 5;         // 4 (32 tokens/block-iter)
    const int blk_base = blockIdx.x * tokens_per_block;
    const float2* __restrict__ W2 = (const float2*)Wl;

    for (int it = 0; it < iters; ++it) {
        const int tb = blk_base + it * 32 + wave * 8;   // this wave's 8 tokens

        // stage emb rows for 8 tokens: 1024 contiguous bytes, one float4/lane
        *(float4*)&KLw[lane * 4] = *(const float4*)(emb + tb * 32 + lane * 4);

        // prefetch q in PHASE-2 layout: token t2, head hh, k in [kh*16, kh*16+16)
        float4 q4[4];
        {
            const float* qp = hid + (tb + t2) * 128 + hh * 32 + kh * 16;
            #pragma unroll
            for (int j = 0; j < 4; ++j)
                q4[j] = *(const float4*)(qp + j * 4);
        }

        // same-wave producer->consumer on staged emb
        __asm__ volatile("s_waitcnt lgkmcnt(0)" ::: "memory");

        float kacc[4][4] = {{0.f,0.f,0.f,0.f},{0.f,0.f,0.f,0.f},
                            {0.f,0.f,0.f,0.f},{0.f,0.f,0.f,0.f}};
        float vacc[4] = {0.f, 0.f, 0.f, 0.f};

        #pragma unroll 8
        for (int dp = 0; dp < 16; ++dp) {
            const float2 w0 = W2[dp * 160 + k];
            const float2 w1 = W2[dp * 160 + 32 + k];
            const float2 w2 = W2[dp * 160 + 64 + k];
            const float2 w3 = W2[dp * 160 + 96 + k];
            const float2 wv = W2[dp * 160 + 128 + k];
            #pragma unroll
            for (int t = 0; t < 4; ++t) {
                const float2 e2 = *(const float2*)&KLw[(mytok + t) * 32 + 2 * dp];
                kacc[t][0] = fmaf(e2.y, w0.y, fmaf(e2.x, w0.x, kacc[t][0]));
                kacc[t][1] = fmaf(e2.y, w1.y, fmaf(e2.x, w1.x, kacc[t][1]));
                kacc[t][2] = fmaf(e2.y, w2.y, fmaf(e2.x, w2.x, kacc[t][2]));
                kacc[t][3] = fmaf(e2.y, w3.y, fmaf(e2.x, w3.x, kacc[t][3]));
                vacc[t]    = fmaf(e2.y, wv.y, fmaf(e2.x, wv.x, vacc[t]));
            }
        }

        // write kk = kacc + bk into swizzled KL rows (overwrites emb stage; all
        // e2 reads were issued earlier -> safe, DS ops are in-order per wave)
        {
            const int cblk = k >> 2, ksub = k & 3;
            #pragma unroll
            for (int t = 0; t < 4; ++t) {
                #pragma unroll
                for (int h = 0; h < 4; ++h) {
                    const int row = h2 * 16 + t * 4 + h;
                    KLw[row * 32 + (((cblk ^ (row & 7)) << 2) | ksub)] =
                        kacc[t][h] + bk_r[h];
                }
            }
        }
        #pragma unroll
        for (int t = 0; t < 4; ++t) vacc[t] += bv_r;

        __asm__ volatile("s_waitcnt lgkmcnt(0)" ::: "memory");

        // ---- phase 2: in-lane reductions, lane = (r2, kh) ----
        float A = 0.f, Bq = 0.f, C = 0.f;
        #pragma unroll
        for (int j = 0; j < 4; ++j) {
            const int cblk = kh * 4 + j;
            const float4 kk4 = *(const float4*)&KLw[r2 * 32 + ((cblk ^ sw2) << 2)];
            const float4 g4  = *(const float4*)&g12L[hh * 36 + kh * 16 + j * 4];
            const float4 q   = q4[j];
            A  = fmaf(kk4.x, kk4.x, A);
            A  = fmaf(kk4.y, kk4.y, A);
            A  = fmaf(kk4.z, kk4.z, A);
            A  = fmaf(kk4.w, kk4.w, A);
            Bq = fmaf(q.x, q.x, Bq);
            Bq = fmaf(q.y, q.y, Bq);
            Bq = fmaf(q.z, q.z, Bq);
            Bq = fmaf(q.w, q.w, Bq);
            C  = fmaf(kk4.x, q.x * g4.x, C);
            C  = fmaf(kk4.y, q.y * g4.y, C);
            C  = fmaf(kk4.z, q.z * g4.z, C);
            C  = fmaf(kk4.w, q.w * g4.w, C);
        }
        // combine the two k-halves (lane g <-> g^32)
        A  += __shfl_xor(A, 32);
        Bq += __shfl_xor(Bq, 32);
        C  += __shfl_xor(C, 32);

        // gate math ONCE per (t,h) (identical formula to R5)
        float g = C * SQRT32 * __builtin_amdgcn_rsqf(A + EPS32)
                             * __builtin_amdgcn_rsqf(Bq + EPS32);
        float rr = copysignf(sqrtf(fmaxf(fabsf(g), 1e-6f)), g);
        float gl = 1.0f / (1.0f + __builtin_amdgcn_exp2f(-rr * LOG2E));
        if (kh == 0) GL[wave][r2] = gl;

        __asm__ volatile("s_waitcnt lgkmcnt(0)" ::: "memory");

        // ---- output in k-layout (coalesced, unchanged pattern) ----
        const int ob = (tb + mytok) * 128 + k;
        #pragma unroll
        for (int t = 0; t < 4; ++t) {
            const float4 gt = *(const float4*)&GL[wave][h2 * 16 + t * 4];
            out[ob + t * 128]      = gt.x * vacc[t];
            out[ob + t * 128 + 32] = gt.y * vacc[t];
            out[ob + t * 128 + 64] = gt.z * vacc[t];
            out[ob + t * 128 + 96] = gt.w * vacc[t];
        }
    }
}

extern "C" void kernel_launch(void* const* d_in, const int* in_sizes, int n_in,
                              void* d_out, int out_size, void* d_ws, size_t ws_size,
                              hipStream_t stream) {
    const float* emb = (const float*)d_in[0];
    const float* hid = (const float*)d_in[1];
    const float* Wv  = (const float*)d_in[2];
    const float* bv  = (const float*)d_in[3];
    const float* Wk  = (const float*)d_in[4];
    const float* bk  = (const float*)d_in[5];
    const float* g1  = (const float*)d_in[6];
    const float* g2  = (const float*)d_in[7];
    float* out = (float*)d_out;
    const int ntok = in_sizes[0] / 32;   // 262144
    engram_kernel<<<GRID, 256, 0, stream>>>(emb, hid, Wv, bv, Wk, bk, g1, g2,
                                            out, ntok);
}